// Round 8
// baseline (157.580 us; speedup 1.0000x reference)
//
#include <hip/hip_runtime.h>

// Batched 3D affine spatial transformer: vol [B=4,160,192,160,1] fp32, trf [4,4,4] fp32.
// R12: R11 = 51.2us, FETCH 109MB vs 77MB ideal. The surviving waste is cross-XCD halo
// duplication: default dispatch puts stride-8 blocks on each XCD (no slab overlap ->
// every halo line fetched by 2-3 XCD L2s). Fix (T1, isolated): 1D grid + bijective
// chunked XCD swizzle (XCD k owns blocks [k*2400,(k+1)*2400)): co-resident blocks tile
// the h/w plane contiguously (h/w halos dedupe in L2) and a full by-layer's staged
// input per XCD (~1MB) < 4MB L2 so the d-halo (the 2x duplication) dedupes too.
// Everything else identical to R11. FETCH_SIZE is the attribution tripwire.
constexpr int D = 160, H = 192, W = 160, B = 4;
constexpr int V  = D * H * W;
constexpr int HW = H * W;
constexpr int VPT = 4;                 // output voxels per thread along d
constexpr int TW  = 32, TH = 8;        // output tile in (w,h); block = (32,8)
constexpr int GXW = W / TW;            // 5
constexpr int GXH = H / TH;            // 24
constexpr int GX  = GXH * GXW;         // 120 h/w tiles
constexpr int GY  = D / VPT;           // 40 d-blocks
constexpr int NWG = GX * GY * B;       // 19200
constexpr int NXCD = 8;
constexpr int CPX  = NWG / NXCD;       // 2400 (exact -> bijective)
constexpr int SD_CAP = 10, SH_CAP = 12, SW_PAD = 44;   // 44 % 4 == 0 (lane-16B rule)
constexpr int PLANE = SH_CAP * SW_PAD;            // 528 floats
constexpr int LDS_FLOATS = SD_CAP * PLANE;        // 5280 floats = 21120 B -> 7 blk/CU

struct DimS { int i0; float w0; };

// Equivalent to neuron.utils interpn clipping (verified R3):
//   c = clip(loc,0,max); i0 = min((int)c, maxi-1); i1 = i0+1; w0 = (i0+1) - c.
__device__ __forceinline__ DimS prep(float loc, float maxv, int maxi) {
    float c  = __builtin_amdgcn_fmed3f(loc, 0.0f, maxv);   // clamp, 1 VALU
    int  i0  = min((int)c, maxi - 1);
    DimS s;
    s.i0 = i0;
    s.w0 = (float)(i0 + 1) - c;
    return s;
}

__device__ __forceinline__ float lerp3(DimS sd, DimS sh, DimS sw,
                                       float2 v00, float2 v01,
                                       float2 v10, float2 v11) {
    const float pd00 = fmaf(sw.w0, v00.x - v00.y, v00.y);
    const float pd01 = fmaf(sw.w0, v01.x - v01.y, v01.y);
    const float pd10 = fmaf(sw.w0, v10.x - v10.y, v10.y);
    const float pd11 = fmaf(sw.w0, v11.x - v11.y, v11.y);
    const float q0 = fmaf(sh.w0, pd00 - pd01, pd01);
    const float q1 = fmaf(sh.w0, pd10 - pd11, pd11);
    return fmaf(sd.w0, q0 - q1, q1);
}

__device__ __forceinline__ float2 ld2_lds(const float* l) {   // 4B-aligned 8B LDS read
    float2 v;
    __builtin_memcpy(&v, l, 8);        // -> ds_read2_b32 (or b64 when provably aligned)
    return v;
}

__device__ __forceinline__ float trilerp_g(const float* __restrict__ vb,
                                           DimS sd, DimS sh, DimS sw) {
    const float* p0 = vb + ((sd.i0 * H + sh.i0) * W + sw.i0);
    float2 v00, v01, v10, v11;
    __builtin_memcpy(&v00, p0,          8);
    __builtin_memcpy(&v01, p0 + W,      8);
    __builtin_memcpy(&v10, p0 + HW,     8);
    __builtin_memcpy(&v11, p0 + HW + W, 8);
    return lerp3(sd, sh, sw, v00, v01, v10, v11);
}

// Async global->LDS, 16B/lane (global_load_lds_dwordx4). LDS dest is wave-uniform
// base + lane*16 (HW rule); source address is per-lane. Inactive lanes do nothing.
__device__ __forceinline__ void gload_lds16(const float* g, float* l) {
    __builtin_amdgcn_global_load_lds(
        (const __attribute__((address_space(1))) void*)g,
        (__attribute__((address_space(3))) void*)l,
        16, 0, 0);
}

__global__ __launch_bounds__(256) void st_affine_kernel(
        const float* __restrict__ vol, const float* __restrict__ trf,
        float* __restrict__ out) {
    __shared__ float sm[LDS_FLOATS];

    // ---- chunked XCD swizzle: HW assigns XCD = blockIdx.x % 8; give XCD k the
    // contiguous logical range [k*CPX, (k+1)*CPX). Bijective since NWG % 8 == 0. ----
    const int id  = blockIdx.x;
    const int nid = (id & (NXCD - 1)) * CPX + (id >> 3);
    const int bz  = nid / (GX * GY);
    const int rem = nid - bz * (GX * GY);
    const int by  = rem / GX;
    const int bx  = rem - by * GX;

    const int b  = bz;
    const int d0 = by * VPT;
    const int hblk = bx / GXW;
    const int wblk = bx - hblk * GXW;
    const int w0 = wblk * TW, h0 = hblk * TH;

    const float* __restrict__ A = trf + b * 16;   // wave-uniform -> scalar loads
    const float a00 = A[0], a01 = A[1], a02 = A[2],  a03 = A[3];
    const float a10 = A[4], a11 = A[5], a12 = A[6],  a13 = A[7];
    const float a20 = A[8], a21 = A[9], a22 = A[10], a23 = A[11];

    constexpr float cd = (D - 1) * 0.5f;
    constexpr float ch = (H - 1) * 0.5f;
    constexpr float cw = (W - 1) * 0.5f;

    // ---- input coords at the tile origin (voxel (d0,h0,w0)) ----
    const float md0 = (float)d0 - cd, mh0 = (float)h0 - ch, mw0 = (float)w0 - cw;
    const float od = cd + fmaf(a00, md0, fmaf(a01, mh0, fmaf(a02, mw0, a03)));
    const float oh = ch + fmaf(a10, md0, fmaf(a11, mh0, fmaf(a12, mw0, a13)));
    const float ow = cw + fmaf(a20, md0, fmaf(a21, mh0, fmaf(a22, mw0, a23)));

    // ---- block-uniform input bbox (affine -> extremes at tile corners) ----
    const float Ed = (float)(VPT - 1), Eh = (float)(TH - 1), Ew = (float)(TW - 1);
    const float dn = od + fminf(a00*Ed,0.f) + fminf(a01*Eh,0.f) + fminf(a02*Ew,0.f);
    const float dx = od + fmaxf(a00*Ed,0.f) + fmaxf(a01*Eh,0.f) + fmaxf(a02*Ew,0.f);
    const float hn = oh + fminf(a10*Ed,0.f) + fminf(a11*Eh,0.f) + fminf(a12*Ew,0.f);
    const float hx = oh + fmaxf(a10*Ed,0.f) + fmaxf(a11*Eh,0.f) + fmaxf(a12*Ew,0.f);
    const float wn = ow + fminf(a20*Ed,0.f) + fminf(a21*Eh,0.f) + fminf(a22*Ew,0.f);
    const float wx = ow + fmaxf(a20*Ed,0.f) + fmaxf(a21*Eh,0.f) + fmaxf(a22*Ew,0.f);

    // lo = min i0 over tile, hi = max i1 over tile ((int)clip is monotone in loc)
    const int lo_d = min((int)__builtin_amdgcn_fmed3f(dn, 0.f, (float)(D-1)), D - 2);
    const int hi_d = min((int)__builtin_amdgcn_fmed3f(dx, 0.f, (float)(D-1)), D - 2) + 1;
    const int lo_h = min((int)__builtin_amdgcn_fmed3f(hn, 0.f, (float)(H-1)), H - 2);
    const int hi_h = min((int)__builtin_amdgcn_fmed3f(hx, 0.f, (float)(H-1)), H - 2) + 1;
    const int lo_w = min((int)__builtin_amdgcn_fmed3f(wn, 0.f, (float)(W-1)), W - 2);
    const int hi_w = min((int)__builtin_amdgcn_fmed3f(wx, 0.f, (float)(W-1)), W - 2) + 1;
    const int lo_w_al = lo_w & ~3;                 // 16B-aligned slab origin in w
    const int SDn = hi_d - lo_d + 1;
    const int SHn = hi_h - lo_h + 1;
    const int SWa = hi_w - lo_w_al + 1;            // aligned-origin w extent

    // ---- per-voxel coords for k=0; voxel k adds k*column0(A) ----
    const float fy = (float)threadIdx.y, fx = (float)threadIdx.x;
    float ld = fmaf(a01, fy, fmaf(a02, fx, od));
    float lh = fmaf(a11, fy, fmaf(a12, fx, oh));
    float lw = fmaf(a21, fy, fmaf(a22, fx, ow));

    const float* __restrict__ vb = vol + (size_t)b * V;
    // Block-uniform store base (SGPR) + per-thread 32-bit offset -> saddr stores.
    float* __restrict__ ob = out + (size_t)b * V + (size_t)d0 * HW;
    const int oofs = (h0 + threadIdx.y) * W + w0 + threadIdx.x;

    // idx+1 needs col <= SW_PAD-1, idx+SW_PAD needs row <= SH_CAP-1, +PLANE needs
    // plane <= SD_CAP-1  =>  fit iff SDn<=SD_CAP && SHn<=SH_CAP && SWa<=SW_PAD.
    if (SDn <= SD_CAP && SHn <= SH_CAP && SWa <= SW_PAD) {
        // ---- LDS path: linear 16B/lane slab staging, then LDS gather ----
        const int tid  = threadIdx.y * TW + threadIdx.x;
        const int wv   = tid >> 6;          // wave id 0..3
        const int lane = tid & 63;
        const int base_off = (lo_d * H + lo_h) * W + lo_w_al;   // 16B-aligned
        const int lim = SDn * PLANE;        // stage only the z-planes we need
        // Instruction i covers slab floats [i*256, i*256+256); wave w takes i=w,w+4,...
        // ceil(lim/256) <= ceil(5280/256) = 21 instructions total, <=6 per wave.
        for (int t = 0; t < 6; ++t) {
            const int i  = wv + t * 4;
            const int Lb = i * 256;
            if (Lb >= lim) break;           // wave-uniform exit
            const int L = Lb + lane * 4;
            if (L < lim) {                  // partial last instruction
                const int z = L / PLANE;    // magic-mul division (constants)
                const int r = L - z * PLANE;
                const int y = r / SW_PAD;
                const int x = r - y * SW_PAD;
                // 44%4==0 => each lane's 4 floats stay inside one slab row.
                // Rows y>=SHn would fetch NEW addresses (R10: +45MB HBM) -> clamp the
                // SOURCE to row SHn-1: dup loads hit L1/L2 (just-fetched lines), and
                // those LDS slots are never read (sh.i0+1 <= SHn-1). Source addr of
                // global_load_lds is per-lane, so per-lane clamp is legal.
                const int ys  = min(y, SHn - 1);
                const int off = min(base_off + (z * H + ys) * W + x, V - 4);
                gload_lds16(vb + off, sm + Lb);
            }
        }
        __syncthreads();                    // drains vmcnt before s_barrier

        const int offL = (lo_d * SH_CAP + lo_h) * SW_PAD + lo_w_al;
#pragma unroll
        for (int k = 0; k < VPT; ++k) {
            const DimS sd = prep(ld, (float)(D - 1), D - 1);
            const DimS sh = prep(lh, (float)(H - 1), H - 1);
            const DimS sw = prep(lw, (float)(W - 1), W - 1);
            const int idx = (sd.i0 * SH_CAP + sh.i0) * SW_PAD + sw.i0 - offL;
            const float* p = sm + idx;
            const float2 v00 = ld2_lds(p);
            const float2 v01 = ld2_lds(p + SW_PAD);
            const float2 v10 = ld2_lds(p + PLANE);
            const float2 v11 = ld2_lds(p + PLANE + SW_PAD);
            const float r = lerp3(sd, sh, sw, v00, v01, v10, v11);
            __builtin_nontemporal_store(r, ob + oofs + k * HW);
            ld += a00; lh += a10; lw += a20;
        }
    } else {
        // ---- fallback: R4-verified global-gather path (identical arithmetic) ----
#pragma unroll
        for (int k = 0; k < VPT; ++k) {
            const DimS sd = prep(ld, (float)(D - 1), D - 1);
            const DimS sh = prep(lh, (float)(H - 1), H - 1);
            const DimS sw = prep(lw, (float)(W - 1), W - 1);
            const float r = trilerp_g(vb, sd, sh, sw);
            __builtin_nontemporal_store(r, ob + oofs + k * HW);
            ld += a00; lh += a10; lw += a20;
        }
    }
}

extern "C" void kernel_launch(void* const* d_in, const int* in_sizes, int n_in,
                              void* d_out, int out_size, void* d_ws, size_t ws_size,
                              hipStream_t stream) {
    const float* vol = (const float*)d_in[0];
    const float* trf = (const float*)d_in[1];
    float* out = (float*)d_out;

    dim3 grid(NWG, 1, 1);               // 19200 blocks, chunked-XCD swizzled in-kernel
    dim3 block(TW, TH, 1);
    st_affine_kernel<<<grid, block, 0, stream>>>(vol, trf, out);
}

// Round 9
// 147.819 us; speedup vs baseline: 1.0660x; 1.0660x over previous
//
#include <hip/hip_runtime.h>

// Batched 3D affine spatial transformer: vol [B=4,160,192,160,1] fp32, trf [4,4,4] fp32.
// R13: R12's chunked-XCD swizzle cut FETCH 109->37MB yet dur REGRESSED 51->59us ->
// traffic is L3-absorbed and was never the wall; schedule-perturbing dedupe loses
// (same family as R9). Swizzles closed; back to R11's 3D grid. The real cost split at
// R11: ~35-40% per-block serial overhead (setup + one vmcnt(0) drain) + per-voxel
// work, with d-halo duplication the worst amortization (10 staged planes / 4 output
// planes = 2.5x). Fix: VPT 4->8. Halves block count (overhead/output halves), staged
// bytes/voxel 20.6->13.1 (d-dup 1.75x). LDS 29.6KB -> 5 blk/CU (20 waves/CU; R7<->R8
// measured 24->32 waves worth only ~1us, so bounded downside). SD_CAP=14 covers
// typical VPT=8 d-spans; oversize blocks take the bit-identical global fallback.
constexpr int D = 160, H = 192, W = 160, B = 4;
constexpr int V  = D * H * W;
constexpr int HW = H * W;
constexpr int VPT = 8;                 // output voxels per thread along d
constexpr int TW  = 32, TH = 8;        // output tile in (w,h); block = (32,8)
constexpr int GXW = W / TW;            // 5
constexpr int GXH = H / TH;            // 24
constexpr int SD_CAP = 14, SH_CAP = 12, SW_PAD = 44;   // 44 % 4 == 0 (lane-16B rule)
constexpr int PLANE = SH_CAP * SW_PAD;            // 528 floats
constexpr int LDS_FLOATS = SD_CAP * PLANE;        // 7392 floats = 29568 B -> 5 blk/CU

struct DimS { int i0; float w0; };

// Equivalent to neuron.utils interpn clipping (verified R3):
//   c = clip(loc,0,max); i0 = min((int)c, maxi-1); i1 = i0+1; w0 = (i0+1) - c.
__device__ __forceinline__ DimS prep(float loc, float maxv, int maxi) {
    float c  = __builtin_amdgcn_fmed3f(loc, 0.0f, maxv);   // clamp, 1 VALU
    int  i0  = min((int)c, maxi - 1);
    DimS s;
    s.i0 = i0;
    s.w0 = (float)(i0 + 1) - c;
    return s;
}

__device__ __forceinline__ float lerp3(DimS sd, DimS sh, DimS sw,
                                       float2 v00, float2 v01,
                                       float2 v10, float2 v11) {
    const float pd00 = fmaf(sw.w0, v00.x - v00.y, v00.y);
    const float pd01 = fmaf(sw.w0, v01.x - v01.y, v01.y);
    const float pd10 = fmaf(sw.w0, v10.x - v10.y, v10.y);
    const float pd11 = fmaf(sw.w0, v11.x - v11.y, v11.y);
    const float q0 = fmaf(sh.w0, pd00 - pd01, pd01);
    const float q1 = fmaf(sh.w0, pd10 - pd11, pd11);
    return fmaf(sd.w0, q0 - q1, q1);
}

__device__ __forceinline__ float2 ld2_lds(const float* l) {   // 4B-aligned 8B LDS read
    float2 v;
    __builtin_memcpy(&v, l, 8);        // -> ds_read2_b32 (or b64 when provably aligned)
    return v;
}

__device__ __forceinline__ float trilerp_g(const float* __restrict__ vb,
                                           DimS sd, DimS sh, DimS sw) {
    const float* p0 = vb + ((sd.i0 * H + sh.i0) * W + sw.i0);
    float2 v00, v01, v10, v11;
    __builtin_memcpy(&v00, p0,          8);
    __builtin_memcpy(&v01, p0 + W,      8);
    __builtin_memcpy(&v10, p0 + HW,     8);
    __builtin_memcpy(&v11, p0 + HW + W, 8);
    return lerp3(sd, sh, sw, v00, v01, v10, v11);
}

// Async global->LDS, 16B/lane (global_load_lds_dwordx4). LDS dest is wave-uniform
// base + lane*16 (HW rule); source address is per-lane. Inactive lanes do nothing.
__device__ __forceinline__ void gload_lds16(const float* g, float* l) {
    __builtin_amdgcn_global_load_lds(
        (const __attribute__((address_space(1))) void*)g,
        (__attribute__((address_space(3))) void*)l,
        16, 0, 0);
}

__global__ __launch_bounds__(256) void st_affine_kernel(
        const float* __restrict__ vol, const float* __restrict__ trf,
        float* __restrict__ out) {
    __shared__ float sm[LDS_FLOATS];

    const int b  = blockIdx.z;
    const int d0 = blockIdx.y * VPT;
    const int hblk = blockIdx.x / GXW;
    const int wblk = blockIdx.x - hblk * GXW;
    const int w0 = wblk * TW, h0 = hblk * TH;

    const float* __restrict__ A = trf + b * 16;   // wave-uniform -> scalar loads
    const float a00 = A[0], a01 = A[1], a02 = A[2],  a03 = A[3];
    const float a10 = A[4], a11 = A[5], a12 = A[6],  a13 = A[7];
    const float a20 = A[8], a21 = A[9], a22 = A[10], a23 = A[11];

    constexpr float cd = (D - 1) * 0.5f;
    constexpr float ch = (H - 1) * 0.5f;
    constexpr float cw = (W - 1) * 0.5f;

    // ---- input coords at the tile origin (voxel (d0,h0,w0)) ----
    const float md0 = (float)d0 - cd, mh0 = (float)h0 - ch, mw0 = (float)w0 - cw;
    const float od = cd + fmaf(a00, md0, fmaf(a01, mh0, fmaf(a02, mw0, a03)));
    const float oh = ch + fmaf(a10, md0, fmaf(a11, mh0, fmaf(a12, mw0, a13)));
    const float ow = cw + fmaf(a20, md0, fmaf(a21, mh0, fmaf(a22, mw0, a23)));

    // ---- block-uniform input bbox (affine -> extremes at tile corners) ----
    const float Ed = (float)(VPT - 1), Eh = (float)(TH - 1), Ew = (float)(TW - 1);
    const float dn = od + fminf(a00*Ed,0.f) + fminf(a01*Eh,0.f) + fminf(a02*Ew,0.f);
    const float dx = od + fmaxf(a00*Ed,0.f) + fmaxf(a01*Eh,0.f) + fmaxf(a02*Ew,0.f);
    const float hn = oh + fminf(a10*Ed,0.f) + fminf(a11*Eh,0.f) + fminf(a12*Ew,0.f);
    const float hx = oh + fmaxf(a10*Ed,0.f) + fmaxf(a11*Eh,0.f) + fmaxf(a12*Ew,0.f);
    const float wn = ow + fminf(a20*Ed,0.f) + fminf(a21*Eh,0.f) + fminf(a22*Ew,0.f);
    const float wx = ow + fmaxf(a20*Ed,0.f) + fmaxf(a21*Eh,0.f) + fmaxf(a22*Ew,0.f);

    // lo = min i0 over tile, hi = max i1 over tile ((int)clip is monotone in loc)
    const int lo_d = min((int)__builtin_amdgcn_fmed3f(dn, 0.f, (float)(D-1)), D - 2);
    const int hi_d = min((int)__builtin_amdgcn_fmed3f(dx, 0.f, (float)(D-1)), D - 2) + 1;
    const int lo_h = min((int)__builtin_amdgcn_fmed3f(hn, 0.f, (float)(H-1)), H - 2);
    const int hi_h = min((int)__builtin_amdgcn_fmed3f(hx, 0.f, (float)(H-1)), H - 2) + 1;
    const int lo_w = min((int)__builtin_amdgcn_fmed3f(wn, 0.f, (float)(W-1)), W - 2);
    const int hi_w = min((int)__builtin_amdgcn_fmed3f(wx, 0.f, (float)(W-1)), W - 2) + 1;
    const int lo_w_al = lo_w & ~3;                 // 16B-aligned slab origin in w
    const int SDn = hi_d - lo_d + 1;
    const int SHn = hi_h - lo_h + 1;
    const int SWa = hi_w - lo_w_al + 1;            // aligned-origin w extent

    // ---- per-voxel coords for k=0; voxel k adds k*column0(A) ----
    const float fy = (float)threadIdx.y, fx = (float)threadIdx.x;
    float ld = fmaf(a01, fy, fmaf(a02, fx, od));
    float lh = fmaf(a11, fy, fmaf(a12, fx, oh));
    float lw = fmaf(a21, fy, fmaf(a22, fx, ow));

    const float* __restrict__ vb = vol + (size_t)b * V;
    // Block-uniform store base (SGPR) + per-thread 32-bit offset -> saddr stores.
    float* __restrict__ ob = out + (size_t)b * V + (size_t)d0 * HW;
    const int oofs = (h0 + threadIdx.y) * W + w0 + threadIdx.x;

    // idx+1 needs col <= SW_PAD-1, idx+SW_PAD needs row <= SH_CAP-1, +PLANE needs
    // plane <= SD_CAP-1  =>  fit iff SDn<=SD_CAP && SHn<=SH_CAP && SWa<=SW_PAD.
    if (SDn <= SD_CAP && SHn <= SH_CAP && SWa <= SW_PAD) {
        // ---- LDS path: linear 16B/lane slab staging, then LDS gather ----
        const int tid  = threadIdx.y * TW + threadIdx.x;
        const int wv   = tid >> 6;          // wave id 0..3
        const int lane = tid & 63;
        const int base_off = (lo_d * H + lo_h) * W + lo_w_al;   // 16B-aligned
        const int lim = SDn * PLANE;        // stage only the z-planes we need
        // Instruction i covers slab floats [i*256, i*256+256); wave w takes i=w,w+4,...
        // ceil(lim/256) <= ceil(7392/256) = 29 instructions total, <=8 per wave.
        for (int t = 0; t < 8; ++t) {
            const int i  = wv + t * 4;
            const int Lb = i * 256;
            if (Lb >= lim) break;           // wave-uniform exit
            const int L = Lb + lane * 4;
            if (L < lim) {                  // partial last instruction
                const int z = L / PLANE;    // magic-mul division (constants)
                const int r = L - z * PLANE;
                const int y = r / SW_PAD;
                const int x = r - y * SW_PAD;
                // 44%4==0 => each lane's 4 floats stay inside one slab row.
                // Rows y>=SHn would fetch NEW addresses (R10: +45MB) -> clamp the
                // SOURCE to row SHn-1: dup loads hit L1/L2 (just-fetched lines), and
                // those LDS slots are never read (sh.i0+1 <= SHn-1). Source addr of
                // global_load_lds is per-lane, so per-lane clamp is legal.
                const int ys  = min(y, SHn - 1);
                const int off = min(base_off + (z * H + ys) * W + x, V - 4);
                gload_lds16(vb + off, sm + Lb);
            }
        }
        __syncthreads();                    // drains vmcnt before s_barrier

        const int offL = (lo_d * SH_CAP + lo_h) * SW_PAD + lo_w_al;
#pragma unroll
        for (int k = 0; k < VPT; ++k) {
            const DimS sd = prep(ld, (float)(D - 1), D - 1);
            const DimS sh = prep(lh, (float)(H - 1), H - 1);
            const DimS sw = prep(lw, (float)(W - 1), W - 1);
            const int idx = (sd.i0 * SH_CAP + sh.i0) * SW_PAD + sw.i0 - offL;
            const float* p = sm + idx;
            const float2 v00 = ld2_lds(p);
            const float2 v01 = ld2_lds(p + SW_PAD);
            const float2 v10 = ld2_lds(p + PLANE);
            const float2 v11 = ld2_lds(p + PLANE + SW_PAD);
            const float r = lerp3(sd, sh, sw, v00, v01, v10, v11);
            __builtin_nontemporal_store(r, ob + oofs + k * HW);
            ld += a00; lh += a10; lw += a20;
        }
    } else {
        // ---- fallback: R4-verified global-gather path (identical arithmetic) ----
#pragma unroll
        for (int k = 0; k < VPT; ++k) {
            const DimS sd = prep(ld, (float)(D - 1), D - 1);
            const DimS sh = prep(lh, (float)(H - 1), H - 1);
            const DimS sw = prep(lw, (float)(W - 1), W - 1);
            const float r = trilerp_g(vb, sd, sh, sw);
            __builtin_nontemporal_store(r, ob + oofs + k * HW);
            ld += a00; lh += a10; lw += a20;
        }
    }
}

extern "C" void kernel_launch(void* const* d_in, const int* in_sizes, int n_in,
                              void* d_out, int out_size, void* d_ws, size_t ws_size,
                              hipStream_t stream) {
    const float* vol = (const float*)d_in[0];
    const float* trf = (const float*)d_in[1];
    float* out = (float*)d_out;

    dim3 grid(GXH * GXW, D / VPT, B);   // (120, 20, 4) = 9600 blocks
    dim3 block(TW, TH, 1);
    st_affine_kernel<<<grid, block, 0, stream>>>(vol, trf, out);
}